// Round 1
// baseline (28.730 us; speedup 1.0000x reference)
//
#include <hip/hip_runtime.h>

#define HH 128
#define WW 192
#define CIN 8
#define NPARAM 169
// param layout: w0[8][10] @0, w1[8][8] @80, w2[8] @144, b0[8] @152, b1[8] @160, b2 @168

__global__ __launch_bounds__(256) void dmh_fused_kernel(
    const float* __restrict__ mask_feats,   // (4,8,128,192)
    const float* __restrict__ params,       // (128,169)
    const float* __restrict__ locs,         // (128,2)
    const float* __restrict__ soi,          // (5,)
    const int*   __restrict__ im_inds,      // (128,)
    const int*   __restrict__ fpn_levels,   // (128,)
    const int*   __restrict__ stride_p,     // scalar (=8)
    float*       __restrict__ out)          // (128,1,256,384)
{
    const int tid = threadIdx.x;
    const int c0 = blockIdx.x * 64;   // source col tile origin
    const int r0 = blockIdx.y * 32;   // source row tile origin
    const int n  = blockIdx.z;        // instance

    __shared__ float sP[NPARAM];
    __shared__ float tile[33 * 66];   // 33 rows x 65 cols (stride 66)

    if (tid < NPARAM) sP[tid] = params[n * NPARAM + tid];

    const int   stride = *stride_p;                 // 8
    const float half   = 0.5f * (float)stride;      // 4.0
    const float locx = locs[2 * n + 0];
    const float locy = locs[2 * n + 1];
    const int   lvl  = fpn_levels[n];
    const float inv  = 1.0f / soi[lvl];
    const int   im   = im_inds[n];
    const float* fb  = mask_feats + (size_t)im * CIN * HH * WW;

    __syncthreads();

    // ---------- phase 1: per-pixel MLP over the 33x65 halo tile ----------
    // halo row/col -1 and +32/+64 clamp to the map edge, which exactly
    // reproduces the edge-pad semantics of aligned_bilinear.
    float h1[8][9];
    int   foff[9];
    float rx[9], ry[9];
    #pragma unroll
    for (int k = 0; k < 9; ++k) {
        int idx = tid + k * 256; if (idx > 2144) idx = 2144;
        int r = idx / 65, c = idx - r * 65;
        int rr = r0 - 1 + r; rr = rr < 0 ? 0 : (rr > HH - 1 ? HH - 1 : rr);
        int cc = c0 - 1 + c; cc = cc < 0 ? 0 : (cc > WW - 1 ? WW - 1 : cc);
        foff[k] = rr * WW + cc;
        rx[k] = (locx - ((float)(cc * stride) + half)) * inv;
        ry[k] = (locy - ((float)(rr * stride) + half)) * inv;
    }
    #pragma unroll
    for (int o = 0; o < 8; ++o) {
        float b  = sP[152 + o];
        float w0 = sP[o * 10 + 0], w1 = sP[o * 10 + 1];
        #pragma unroll
        for (int k = 0; k < 9; ++k)
            h1[o][k] = fmaf(w0, rx[k], fmaf(w1, ry[k], b));
    }
    #pragma unroll
    for (int ch = 0; ch < 8; ++ch) {
        const float* f = fb + ch * (HH * WW);
        float x[9];
        #pragma unroll
        for (int k = 0; k < 9; ++k) x[k] = f[foff[k]];
        #pragma unroll
        for (int o = 0; o < 8; ++o) {
            float w = sP[o * 10 + 2 + ch];
            #pragma unroll
            for (int k = 0; k < 9; ++k) h1[o][k] = fmaf(w, x[k], h1[o][k]);
        }
    }
    #pragma unroll
    for (int o = 0; o < 8; ++o)
        #pragma unroll
        for (int k = 0; k < 9; ++k) h1[o][k] = fmaxf(h1[o][k], 0.0f);

    float logit[9];
    {
        float b2 = sP[168];
        #pragma unroll
        for (int k = 0; k < 9; ++k) logit[k] = b2;
    }
    #pragma unroll
    for (int o = 0; o < 8; ++o) {         // layer1 channel o, fused layer2
        float acc[9];
        float b = sP[160 + o];
        #pragma unroll
        for (int k = 0; k < 9; ++k) acc[k] = b;
        #pragma unroll
        for (int i = 0; i < 8; ++i) {
            float w = sP[80 + o * 8 + i];
            #pragma unroll
            for (int k = 0; k < 9; ++k) acc[k] = fmaf(w, h1[i][k], acc[k]);
        }
        float w2 = sP[144 + o];
        #pragma unroll
        for (int k = 0; k < 9; ++k)
            logit[k] = fmaf(w2, fmaxf(acc[k], 0.0f), logit[k]);
    }
    #pragma unroll
    for (int k = 0; k < 9; ++k) {
        int idx = tid + k * 256;
        if (idx <= 2144) {
            int r = idx / 65, c = idx - r * 65;
            tile[r * 66 + c] = logit[k];
        }
    }
    __syncthreads();

    // ---------- phase 2: x2 aligned upsample -> 64x128 output tile ----------
    // final[y][x] samples resized[max(y-1,0)][max(x-1,0)] of the x2
    // align-corners resize; with the halo the index math is uniform:
    // i=y-1, rb=i>>1 (arith), fy=i&1, rows {rb, rb+1} weighted {1,0}/{.5,.5}.
    const int kx = tid & 31;          // 32 groups of 4 output cols
    const int g  = tid >> 5;          // 8 row groups
    float* ob = out + ((size_t)n * 256 + 2 * r0) * 384 + 2 * c0 + 4 * kx;
    #pragma unroll
    for (int yy = 0; yy < 8; ++yy) {
        int yt = g * 8 + yy;
        int i  = 2 * r0 + yt - 1;
        int rb = i >> 1;
        int fy = i & 1;
        float wy0 = fy ? 0.5f : 1.0f;
        float wy1 = fy ? 0.5f : 0.0f;
        int lr  = rb - r0 + 1;        // in [0,32]
        int lr2 = lr + fy;            // in [0,32]
        const float* ra = &tile[lr  * 66 + 2 * kx];
        const float* rc = &tile[lr2 * 66 + 2 * kx];
        float t0 = fmaf(wy1, rc[0], wy0 * ra[0]);
        float t1 = fmaf(wy1, rc[1], wy0 * ra[1]);
        float t2 = fmaf(wy1, rc[2], wy0 * ra[2]);
        float4 o4;
        o4.x = 0.5f * (t0 + t1);
        o4.y = t1;
        o4.z = 0.5f * (t1 + t2);
        o4.w = t2;
        *reinterpret_cast<float4*>(ob + (size_t)yt * 384) = o4;
    }
}

extern "C" void kernel_launch(void* const* d_in, const int* in_sizes, int n_in,
                              void* d_out, int out_size, void* d_ws, size_t ws_size,
                              hipStream_t stream) {
    const float* mask_feats = (const float*)d_in[0];
    const float* params     = (const float*)d_in[1];
    const float* locs       = (const float*)d_in[2];
    const float* soi        = (const float*)d_in[3];
    const int*   im_inds    = (const int*)d_in[4];
    const int*   fpn_levels = (const int*)d_in[5];
    const int*   stride_p   = (const int*)d_in[6];
    float* out = (float*)d_out;

    dim3 grid(WW / 64, HH / 32, 128);   // (3, 4, 128)
    dim3 block(256);
    dmh_fused_kernel<<<grid, block, 0, stream>>>(
        mask_feats, params, locs, soi, im_inds, fpn_levels, stride_p, out);
}